// Round 9
// baseline (402.749 us; speedup 1.0000x reference)
//
#include <hip/hip_runtime.h>
#include <math.h>

// Problem constants (match reference)
namespace {
constexpr int Bn = 64;    // batch
constexpr int Dn = 256;   // feature dim
constexpr int Tn = 24;    // words
constexpr int Rn = 17;
constexpr int Sn = Rn * Rn;  // 289 spatial
constexpr float G1 = 4.0f, G2 = 5.0f, G3 = 10.0f;
constexpr float EPSF = 1e-8f;
constexpr float NEGF = -1e30f;
// MFMA-path geometry
constexpr int MT_A = 19;   // GEMM-A m-tiles (304 rows of s)
constexpr int KK_A = 8;    // GEMM-A k-steps (256 = 8*32 over d)
constexpr int DT_B = 16;   // GEMM-B m-tiles (256 rows of d)
constexpr int KK_B = 10;   // GEMM-B k-steps (320 = 10*32 over s)
constexpr int ESTR = 344;  // EH/EL row stride (shorts): 688 B rows
constexpr int PSTR = 305;  // P row stride (floats) inside union
constexpr int TSTR = 293;  // prep LDS tile stride (floats)
// VALU-fallback constants (round-4 kernel, known-correct)
constexpr int WSTR = 24;
constexpr int ASTR = 24;
constexpr int NT = 320;
}

typedef __attribute__((ext_vector_type(8))) short bf16x8;  // 8 bf16 (4 VGPRs)
typedef __attribute__((ext_vector_type(4))) float f32x4;   // 4 fp32 acc

#define MFMA_BF16 __builtin_amdgcn_mfma_f32_16x16x32_bf16

// RNE float -> bf16 bits (bit-twiddle; no NaN inputs here)
__device__ __forceinline__ short f2bf(float x) {
  unsigned u = __float_as_uint(x);
  return (short)((u + 0x7FFFu + ((u >> 16) & 1u)) >> 16);
}
__device__ __forceinline__ float bf2f(short h) {
  return __uint_as_float(((unsigned)(unsigned short)h) << 16);
}

// ---------------------------------------------------------------------------
// Fused prep: blocks [0, Bn*8) handle ctx (A-frags + C-frags via LDS tile);
// blocks [Bn*8, Bn*8+8) handle W-frags. Block 0 also zeroes the completion
// counter used by k_main8's fused loss.
// ---------------------------------------------------------------------------
__global__ __launch_bounds__(256) void kprep_ctx(const float* __restrict__ ctx,
                                                 const float* __restrict__ words,
                                                 short* __restrict__ Ahf,
                                                 short* __restrict__ Alf,
                                                 short* __restrict__ Chf,
                                                 short* __restrict__ Clf,
                                                 short* __restrict__ Whf,
                                                 short* __restrict__ Wlf,
                                                 unsigned* __restrict__ cnt) {
  __shared__ float tile[32][TSTR];  // 37.5 KB
  const int tid = threadIdx.x;
  if (blockIdx.x == 0 && tid == 0) *cnt = 0u;  // reset fused-loss counter

  if (blockIdx.x >= Bn * 8) {
    // ---- W-frags: [i][kk][n][lane][8]; lane holds W[n*16+l15][kk*32+lg*8+e]
    const int wb = blockIdx.x - Bn * 8;  // 0..7
    const int total = Bn * KK_A * 2 * 64;
    for (int gid = wb * 256 + tid; gid < total; gid += 8 * 256) {
      const int lane = gid & 63;
      int f = gid >> 6;
      const int n = f & 1; f >>= 1;
      const int kk = f & 7;
      const int i = f >> 3;
      const int t = n * 16 + (lane & 15);
      const int d0 = kk * 32 + (lane >> 4) * 8;
      bf16x8 hi, lo;
#pragma unroll
      for (int e = 0; e < 8; ++e) {
        float v = (t < Tn) ? words[((size_t)i * Dn + d0 + e) * Tn + t] : 0.f;
        short h = f2bf(v);
        hi[e] = h;
        lo[e] = f2bf(v - bf2f(h));
      }
      *(bf16x8*)&Whf[(size_t)gid * 8] = hi;
      *(bf16x8*)&Wlf[(size_t)gid * 8] = lo;
    }
    return;
  }

  const int b = blockIdx.x >> 3;
  const int d0b = blockIdx.x & 7;   // d-block index (= GEMM-A k-step kkA)
  const int d0 = d0b * 32;
  const int tx = tid & 31, ty = tid >> 5;

  // ---- stage: 32 lanes read 32 consecutive floats per row (coalesced)
  for (int r = ty; r < 32; r += 8) {
    const float* src = ctx + ((size_t)b * Dn + d0 + r) * Sn;
    for (int s = tx; s < Sn; s += 32) tile[r][s] = src[s];
  }
  __syncthreads();

  // ---- emit A-frags: 19 mt x 64 lanes; value e: tile[lg*8+e][mt*16+l15]
  for (int slot = tid; slot < MT_A * 64; slot += 256) {
    const int mt = slot >> 6;
    const int lane = slot & 63;
    const int s = mt * 16 + (lane & 15);
    const int dl = (lane >> 4) * 8;
    bf16x8 hi, lo;
#pragma unroll
    for (int e = 0; e < 8; ++e) {
      float v = (s < Sn) ? tile[dl + e][s] : 0.f;
      short h = f2bf(v);
      hi[e] = h;
      lo[e] = f2bf(v - bf2f(h));
    }
    const size_t gid = ((size_t)(b * MT_A + mt) * KK_A + d0b) * 64 + lane;
    *(bf16x8*)&Ahf[gid * 8] = hi;
    *(bf16x8*)&Alf[gid * 8] = lo;
  }

  // ---- emit C-frags: 2 dt x 10 kk x 64 lanes; value e: tile[dtl*16+l15][s0+e]
  for (int slot = tid; slot < 2 * KK_B * 64; slot += 256) {
    const int lane = slot & 63;
    const int f = slot >> 6;
    const int kk = f % KK_B;
    const int dtl = f / KK_B;
    const int dloc = dtl * 16 + (lane & 15);
    const int s0 = kk * 32 + (lane >> 4) * 8;
    bf16x8 hi, lo;
#pragma unroll
    for (int e = 0; e < 8; ++e) {
      const int s = s0 + e;
      float v = (s < Sn) ? tile[dloc][s] : 0.f;
      short h = f2bf(v);
      hi[e] = h;
      lo[e] = f2bf(v - bf2f(h));
    }
    const size_t gid = ((size_t)(b * DT_B + (d0b * 2 + dtl)) * KK_B + kk) * 64 + lane;
    *(bf16x8*)&Chf[gid * 8] = hi;
    *(bf16x8*)&Clf[gid * 8] = lo;
  }
}

// ---------------------------------------------------------------------------
// Main MFMA kernel: one 512-thread block (8 waves) per (i,b) pair.
// Round-9 deltas: full unroll of kk loops (ILP; VGPR headroom 40->85);
// fused masked log-softmax loss in the LAST block (device-scope counter).
// Fragment layout (guide §3, m89-verified C/D):
//   A: row m = lane&15, k = (lane>>4)*8+e ; B: col n = lane&15, same k
//   C/D: col n = lane&15, row m = (lane>>4)*4 + reg
// ---------------------------------------------------------------------------
__global__ __launch_bounds__(512, 6) void k_main8(
    const short* __restrict__ Ahf, const short* __restrict__ Alf,
    const short* __restrict__ Chf, const short* __restrict__ Clf,
    const short* __restrict__ Whf, const short* __restrict__ Wlf,
    const float* __restrict__ words, const int* __restrict__ cap_lens,
    const int* __restrict__ labels, const int* __restrict__ class_ids,
    unsigned* __restrict__ cnt,
    float* __restrict__ sims, float* __restrict__ out, float* __restrict__ att_out)
{
  __shared__ __align__(16) short U[2][32][ESTR];  // 44,032 B: EH=U[0], EL=U[1]
  __shared__ float inv2s[32];
  __shared__ float redN[Tn], redV[Tn], redW[Tn], redE[Tn];
  __shared__ unsigned lastflag;
  float (*P)[PSTR] = (float (*)[PSTR]) & U[0][0][0];  // aliases U; dead before EH/EL live

  const int bid = blockIdx.x;
  const int i = bid & 63, b = bid >> 6;
  const int tid = threadIdx.x;
  const int lane = tid & 63;
  const int wv = tid >> 6;              // wave 0..7
  const int l15 = lane & 15, lg = lane >> 4;
  const int len = cap_lens[i];

  if (tid < Tn) { redN[tid] = 0.f; redV[tid] = 0.f; redW[tid] = 0.f; }

  // ============ GEMM-A: logits[s][t] = sum_d ctxT[s][d] * W^T[t][d]
  f32x4 acc[3][2];
#pragma unroll
  for (int j = 0; j < 3; ++j) {
    acc[j][0] = f32x4{0.f, 0.f, 0.f, 0.f};
    acc[j][1] = f32x4{0.f, 0.f, 0.f, 0.f};
  }
#pragma unroll
  for (int kk = 0; kk < KK_A; ++kk) {
    const size_t Wb = ((size_t)(i * KK_A + kk) * 2) * 512 + (size_t)lane * 8;
    bf16x8 bh0 = *(const bf16x8*)&Whf[Wb];
    bf16x8 bl0 = *(const bf16x8*)&Wlf[Wb];
    bf16x8 bh1 = *(const bf16x8*)&Whf[Wb + 512];
    bf16x8 bl1 = *(const bf16x8*)&Wlf[Wb + 512];
#pragma unroll
    for (int j = 0; j < 3; ++j) {
      const int mt = wv + j * 8;            // wave's m-tiles: w, w+8, w+16
      if (mt < MT_A) {
        const size_t Ab = ((size_t)(b * MT_A + mt) * KK_A + kk) * 512 + (size_t)lane * 8;
        bf16x8 ah = *(const bf16x8*)&Ahf[Ab];
        bf16x8 al = *(const bf16x8*)&Alf[Ab];
        __builtin_amdgcn_s_setprio(1);
        acc[j][0] = MFMA_BF16(ah, bh0, acc[j][0], 0, 0, 0);
        acc[j][0] = MFMA_BF16(ah, bl0, acc[j][0], 0, 0, 0);
        acc[j][0] = MFMA_BF16(al, bh0, acc[j][0], 0, 0, 0);
        acc[j][1] = MFMA_BF16(ah, bh1, acc[j][1], 0, 0, 0);
        acc[j][1] = MFMA_BF16(ah, bl1, acc[j][1], 0, 0, 0);
        acc[j][1] = MFMA_BF16(al, bh1, acc[j][1], 0, 0, 0);
        __builtin_amdgcn_s_setprio(0);
      }
    }
  }

  // ---- softmax-1 over t (masked t<len), fully in registers; write p1 to P.
  //      Row s = mt*16 + lg*4 + q lives in the 16 lanes of group lg, reg q.
  const int t0 = l15, t1 = 16 + l15;
#pragma unroll
  for (int j = 0; j < 3; ++j) {
    const int mt = wv + j * 8;
    if (mt >= MT_A) continue;
    float mx[4], e0[4], e1[4], sum[4];
#pragma unroll
    for (int q = 0; q < 4; ++q) {
      float a = (t0 < len) ? acc[j][0][q] : NEGF;
      float c = (t1 < len) ? acc[j][1][q] : NEGF;
      mx[q] = fmaxf(a, c);
    }
#pragma unroll
    for (int q = 0; q < 4; ++q) {
      mx[q] = fmaxf(mx[q], __shfl_xor(mx[q], 1));
      mx[q] = fmaxf(mx[q], __shfl_xor(mx[q], 2));
      mx[q] = fmaxf(mx[q], __shfl_xor(mx[q], 4));
      mx[q] = fmaxf(mx[q], __shfl_xor(mx[q], 8));
    }
#pragma unroll
    for (int q = 0; q < 4; ++q) {
      e0[q] = (t0 < len) ? __expf(acc[j][0][q] - mx[q]) : 0.f;
      e1[q] = (t1 < len) ? __expf(acc[j][1][q] - mx[q]) : 0.f;
      sum[q] = e0[q] + e1[q];
    }
#pragma unroll
    for (int q = 0; q < 4; ++q) {
      sum[q] += __shfl_xor(sum[q], 1);
      sum[q] += __shfl_xor(sum[q], 2);
      sum[q] += __shfl_xor(sum[q], 4);
      sum[q] += __shfl_xor(sum[q], 8);
    }
#pragma unroll
    for (int q = 0; q < 4; ++q) {
      const int s = mt * 16 + lg * 4 + q;
      const float inv = 1.f / sum[q];
      if (s < Sn) {
        P[t0][s] = e0[q] * inv;
        if (l15 < 8) P[t1][s] = e1[q] * inv;  // t 16..23
      }
    }
  }
  __syncthreads();  // P complete

  // ---- softmax-2 over s (per t), register-buffered so EH/EL can reuse P's LDS.
  const int t2 = tid >> 4;      // 16 lanes per t
  const int g2i = tid & 15;
  float ev[19];
  float sinv = 0.f;
  if (t2 < Tn) {
    float mx = NEGF;
#pragma unroll
    for (int k = 0; k < 19; ++k) {
      const int s = g2i + 16 * k;
      ev[k] = (s < Sn) ? P[t2][s] : NEGF;
      mx = fmaxf(mx, ev[k]);
    }
    mx = fmaxf(mx, __shfl_xor(mx, 1));
    mx = fmaxf(mx, __shfl_xor(mx, 2));
    mx = fmaxf(mx, __shfl_xor(mx, 4));
    mx = fmaxf(mx, __shfl_xor(mx, 8));
    mx *= G1;  // exact: G1 = 4.0 is a power of two
    float sum = 0.f;
#pragma unroll
    for (int k = 0; k < 19; ++k) {
      const int s = g2i + 16 * k;
      float e = (s < Sn) ? __expf(G1 * ev[k] - mx) : 0.f;
      ev[k] = e;  // overwrite with unnormalized e2
      sum += e;
    }
    sum += __shfl_xor(sum, 1);
    sum += __shfl_xor(sum, 2);
    sum += __shfl_xor(sum, 4);
    sum += __shfl_xor(sum, 8);
    sinv = 1.f / sum;
    if (g2i == 0) inv2s[t2] = sinv;
  }
  __syncthreads();  // all P reads done; U now owned by EH/EL

  // ---- Phase 2: write e2 split-bf16 into EH/EL; zero pad; att_maps on diag.
  if (t2 < Tn) {
#pragma unroll
    for (int k = 0; k < 19; ++k) {
      const int s = g2i + 16 * k;
      if (s < Sn) {
        float e = ev[k];
        short h = f2bf(e);
        U[0][t2][s] = h;
        U[1][t2][s] = f2bf(e - bf2f(h));
      }
    }
    if (i == b) {
      float* ao = att_out + ((size_t)i * Tn + t2) * Sn;
#pragma unroll
      for (int k = 0; k < 19; ++k) {
        const int s = g2i + 16 * k;
        if (s < Sn) ao[s] = ev[k] * sinv;
      }
    }
  }
  // zero k-pad cols [289,320) rows 0..23, and full rows 24..31 (both buffers)
  for (int idx = tid; idx < 24 * 31; idx += 512) {
    const int r = idx / 31, c = 289 + idx % 31;
    U[0][r][c] = 0; U[1][r][c] = 0;
  }
  for (int idx = tid; idx < 8 * ESTR; idx += 512) {
    const int r = 24 + idx / ESTR, c = idx % ESTR;
    U[0][r][c] = 0; U[1][r][c] = 0;
  }
  __syncthreads();

  // ============ GEMM-B: wei[d][t] = sum_s ctx[b][d][s] * e2[t][s]
  f32x4 acc2[2][2];
#pragma unroll
  for (int j = 0; j < 2; ++j) {
    acc2[j][0] = f32x4{0.f, 0.f, 0.f, 0.f};
    acc2[j][1] = f32x4{0.f, 0.f, 0.f, 0.f};
  }
#pragma unroll
  for (int kk = 0; kk < KK_B; ++kk) {
    const int k0 = kk * 32 + lg * 8;
    bf16x8 bh0 = *(const bf16x8*)&U[0][l15][k0];
    bf16x8 bl0 = *(const bf16x8*)&U[1][l15][k0];
    bf16x8 bh1 = *(const bf16x8*)&U[0][16 + l15][k0];
    bf16x8 bl1 = *(const bf16x8*)&U[1][16 + l15][k0];
#pragma unroll
    for (int j = 0; j < 2; ++j) {
      const int dt = wv + j * 8;            // d-tiles: w, w+8
      const size_t Cb = ((size_t)(b * DT_B + dt) * KK_B + kk) * 512 + (size_t)lane * 8;
      bf16x8 ah = *(const bf16x8*)&Chf[Cb];
      bf16x8 al = *(const bf16x8*)&Clf[Cb];
      __builtin_amdgcn_s_setprio(1);
      acc2[j][0] = MFMA_BF16(ah, bh0, acc2[j][0], 0, 0, 0);
      acc2[j][0] = MFMA_BF16(ah, bl0, acc2[j][0], 0, 0, 0);
      acc2[j][0] = MFMA_BF16(al, bh0, acc2[j][0], 0, 0, 0);
      acc2[j][1] = MFMA_BF16(ah, bh1, acc2[j][1], 0, 0, 0);
      acc2[j][1] = MFMA_BF16(ah, bl1, acc2[j][1], 0, 0, 0);
      acc2[j][1] = MFMA_BF16(al, bh1, acc2[j][1], 0, 0, 0);
      __builtin_amdgcn_s_setprio(0);
    }
  }

  // ---- cosine similarity: per t reduce num/|wei|^2/|w|^2 over d
  float pn[2] = {0.f, 0.f}, pv[2] = {0.f, 0.f}, pw[2] = {0.f, 0.f};
#pragma unroll
  for (int nt = 0; nt < 2; ++nt) {
    const int t = nt * 16 + l15;
    const bool tv = (t < Tn);
    const float iv = tv ? inv2s[t] : 0.f;
#pragma unroll
    for (int j = 0; j < 2; ++j) {
#pragma unroll
      for (int q = 0; q < 4; ++q) {
        const int d = (wv + j * 8) * 16 + lg * 4 + q;
        const float wei = acc2[j][nt][q] * iv;
        const float wvv = tv ? words[((size_t)i * Dn + d) * Tn + t] : 0.f;
        pn[nt] = fmaf(wvv, wei, pn[nt]);
        pv[nt] = fmaf(wei, wei, pv[nt]);
        pw[nt] = fmaf(wvv, wvv, pw[nt]);
      }
    }
  }
#pragma unroll
  for (int nt = 0; nt < 2; ++nt) {
    pn[nt] += __shfl_xor(pn[nt], 16); pn[nt] += __shfl_xor(pn[nt], 32);
    pv[nt] += __shfl_xor(pv[nt], 16); pv[nt] += __shfl_xor(pv[nt], 32);
    pw[nt] += __shfl_xor(pw[nt], 16); pw[nt] += __shfl_xor(pw[nt], 32);
  }
  if (lg == 0) {
#pragma unroll
    for (int nt = 0; nt < 2; ++nt) {
      const int t = nt * 16 + l15;
      if (t < Tn) {
        atomicAdd(&redN[t], pn[nt]);
        atomicAdd(&redV[t], pv[nt]);
        atomicAdd(&redW[t], pw[nt]);
      }
    }
  }
  __syncthreads();
  if (tid < Tn) {
    const float den = fmaxf(sqrtf(redW[tid]) * sqrtf(redV[tid]), EPSF);
    const float rs = redN[tid] / den;
    redE[tid] = (tid < len) ? __expf(G2 * rs) : 0.f;
  }
  __syncthreads();
  if (tid == 0) {
    float ssum = 0.f;
#pragma unroll
    for (int t = 0; t < Tn; ++t) ssum += redE[t];
    sims[i * Bn + b] = logf(ssum);
  }
  __syncthreads();

  // ---- fused loss: last block (device-scope counter) computes both losses.
  if (tid == 0) {
    __threadfence();  // release: sims store visible device-wide
    unsigned old = atomicAdd(cnt, 1u);
    lastflag = (old == (unsigned)(Bn * Bn - 1)) ? 1u : 0u;
  }
  __syncthreads();
  if (lastflag && tid < 64) {
    __threadfence();  // acquire: observe all blocks' sims
    const int r = tid;
    const int cr = class_ids[r];
    const int lab = labels[r];

    float m0 = NEGF;
    for (int c = 0; c < Bn; ++c) {
      float v = sims[c * Bn + r] * G3;
      if (class_ids[c] == cr && c != r) v = NEGF;
      m0 = fmaxf(m0, v);
    }
    float se0 = 0.f, tgt0 = 0.f;
    for (int c = 0; c < Bn; ++c) {
      float v = sims[c * Bn + r] * G3;
      if (class_ids[c] == cr && c != r) v = NEGF;
      se0 += __expf(v - m0);
      if (c == lab) tgt0 = v;
    }
    float val0 = tgt0 - (m0 + logf(se0));

    float m1 = NEGF;
    for (int c = 0; c < Bn; ++c) {
      float v = sims[r * Bn + c] * G3;
      if (class_ids[c] == cr && c != r) v = NEGF;
      m1 = fmaxf(m1, v);
    }
    float se1 = 0.f, tgt1 = 0.f;
    for (int c = 0; c < Bn; ++c) {
      float v = sims[r * Bn + c] * G3;
      if (class_ids[c] == cr && c != r) v = NEGF;
      se1 += __expf(v - m1);
      if (c == lab) tgt1 = v;
    }
    float val1 = tgt1 - (m1 + logf(se1));

    for (int off = 1; off < 64; off <<= 1) {
      val0 += __shfl_xor(val0, off);
      val1 += __shfl_xor(val1, off);
    }
    if (r == 0) {
      out[0] = -val0 / (float)Bn;
      out[1] = -val1 / (float)Bn;
    }
  }
}

// ---------------------------------------------------------------------------
// VALU fallback path (round-4 kernels, known-correct) — used if ws too small.
// ---------------------------------------------------------------------------
__device__ __forceinline__ void fma24(float v, const float* __restrict__ row,
                                      float* __restrict__ acc) {
#pragma unroll
  for (int t = 0; t < Tn; ++t) acc[t] = fmaf(v, row[t], acc[t]);
}

__global__ __launch_bounds__(256) void k_transpose(const float* __restrict__ ctx,
                                                   float* __restrict__ ctxT) {
  __shared__ float tile[32][33];
  const int b = blockIdx.z;
  const int x0 = blockIdx.x * 32;
  const int y0 = blockIdx.y * 32;
  const int tx = threadIdx.x, ty = threadIdx.y;
  const float* src = ctx + (size_t)b * Dn * Sn;
  float* dst = ctxT + (size_t)b * Sn * Dn;
#pragma unroll
  for (int k = 0; k < 4; ++k) {
    int y = y0 + ty + k * 8, x = x0 + tx;
    if (x < Sn) tile[ty + k * 8][tx] = src[(size_t)y * Sn + x];
  }
  __syncthreads();
#pragma unroll
  for (int k = 0; k < 4; ++k) {
    int x = x0 + ty + k * 8, y = y0 + tx;
    if (x < Sn) dst[(size_t)x * Dn + y] = tile[tx][ty + k * 8];
  }
}

__global__ __launch_bounds__(NT) void k_main_valu(
    const float* __restrict__ ctx, const float* __restrict__ words,
    const float* __restrict__ g2, int tstr, int sstr,
    const int* __restrict__ cap_lens,
    float* __restrict__ sims, float* __restrict__ att_out)
{
  __shared__ __align__(16) float Wl[Dn * WSTR];
  __shared__ __align__(16) float AT[Sn * ASTR];
  __shared__ float inv2[Tn];
  __shared__ float red[Tn];

  const int bid = blockIdx.x;
  const int i = bid & 63, b = bid >> 6;
  const int tid = threadIdx.x;
  const int len = cap_lens[i];

  {
    const float4* wsrc = (const float4*)(words + (size_t)i * Dn * Tn);
    float4* wdst = (float4*)Wl;
    for (int k = tid; k < Dn * Tn / 4; k += NT) wdst[k] = wsrc[k];
  }
  __syncthreads();

  if (tid < Sn) {
    float acc[Tn];
#pragma unroll
    for (int t = 0; t < Tn; ++t) acc[t] = 0.f;
    const float* cb = ctx + (size_t)b * Dn * Sn + tid;
    float v0 = cb[0], v1 = cb[Sn];
    int d = 0;
    for (; d < Dn - 2; d += 2) {
      float n0 = cb[(size_t)(d + 2) * Sn];
      float n1 = cb[(size_t)(d + 3) * Sn];
      fma24(v0, &Wl[d * WSTR], acc);
      fma24(v1, &Wl[(d + 1) * WSTR], acc);
      v0 = n0; v1 = n1;
    }
    fma24(v0, &Wl[d * WSTR], acc);
    fma24(v1, &Wl[(d + 1) * WSTR], acc);
    float m = NEGF;
#pragma unroll
    for (int t = 0; t < Tn; ++t)
      if (t < len) m = fmaxf(m, acc[t]);
    float sum = 0.f;
#pragma unroll
    for (int t = 0; t < Tn; ++t) {
      float e = (t < len) ? __expf(acc[t] - m) : 0.f;
      acc[t] = e; sum += e;
    }
    const float inv = 1.f / sum;
#pragma unroll
    for (int t = 0; t < Tn; ++t) AT[tid * ASTR + t] = acc[t] * inv;
  }
  __syncthreads();

  if (tid < Tn * 8) {
    const int t = tid >> 3, g = tid & 7;
    float m = NEGF;
    for (int ss = g; ss < Sn; ss += 8) m = fmaxf(m, AT[ss * ASTR + t]);
    m = fmaxf(m, __shfl_xor(m, 1));
    m = fmaxf(m, __shfl_xor(m, 2));
    m = fmaxf(m, __shfl_xor(m, 4));
    m *= G1;
    float sum = 0.f;
    for (int ss = g; ss < Sn; ss += 8) {
      float e = __expf(G1 * AT[ss * ASTR + t] - m);
      AT[ss * ASTR + t] = e;
      sum += e;
    }
    sum += __shfl_xor(sum, 1);
    sum += __shfl_xor(sum, 2);
    sum += __shfl_xor(sum, 4);
    if (g == 0) inv2[t] = 1.f / sum;
  }
  __syncthreads();

  float acc2[Tn];
  if (tid < Dn) {
#pragma unroll
    for (int t = 0; t < Tn; ++t) acc2[t] = 0.f;
    const float* src = g2 + (size_t)b * Dn * Sn + (size_t)tid * tstr;
    const size_t s1 = sstr, s2 = 2 * (size_t)sstr, s3 = 3 * (size_t)sstr,
                 s4 = 4 * (size_t)sstr;
    float p0 = src[0], p1 = src[s1], p2 = src[s2], p3 = src[s3];
    const float* nsrc = src + s4;
    int ss = 0;
    for (; ss < 284; ss += 4) {
      float n0 = nsrc[0], n1 = nsrc[s1], n2 = nsrc[s2], n3 = nsrc[s3];
      fma24(p0, &AT[ss * ASTR], acc2);
      fma24(p1, &AT[(ss + 1) * ASTR], acc2);
      fma24(p2, &AT[(ss + 2) * ASTR], acc2);
      fma24(p3, &AT[(ss + 3) * ASTR], acc2);
      p0 = n0; p1 = n1; p2 = n2; p3 = n3;
      nsrc += s4;
    }
    fma24(p0, &AT[284 * ASTR], acc2);
    fma24(p1, &AT[285 * ASTR], acc2);
    fma24(p2, &AT[286 * ASTR], acc2);
    fma24(p3, &AT[287 * ASTR], acc2);
    {
      float v = src[(size_t)288 * sstr];
      fma24(v, &AT[288 * ASTR], acc2);
    }
#pragma unroll
    for (int t = 0; t < Tn; ++t) acc2[t] *= inv2[t];
  }

  if (i == b) {
#pragma unroll 1
    for (int t = 0; t < Tn; ++t) {
      const float iv = inv2[t];
      for (int ss = tid; ss < Sn; ss += NT)
        att_out[(size_t)i * Tn * Sn + (size_t)t * Sn + ss] = AT[ss * ASTR + t] * iv;
    }
  }
  __syncthreads();

  if (tid < Dn) {
#pragma unroll
    for (int t = 0; t < Tn; ++t) AT[tid * ASTR + t] = acc2[t];
  }
  __syncthreads();

  if (tid < Tn * 8) {
    const int t = tid >> 3, g = tid & 7;
    float num = 0.f, wn = 0.f, vn = 0.f;
    for (int dd = g; dd < Dn; dd += 8) {
      float wvv = Wl[dd * WSTR + t];
      float uv = AT[dd * ASTR + t];
      num = fmaf(wvv, uv, num);
      wn = fmaf(wvv, wvv, wn);
      vn = fmaf(uv, uv, vn);
    }
    num += __shfl_xor(num, 1); num += __shfl_xor(num, 2); num += __shfl_xor(num, 4);
    wn  += __shfl_xor(wn, 1);  wn  += __shfl_xor(wn, 2);  wn  += __shfl_xor(wn, 4);
    vn  += __shfl_xor(vn, 1);  vn  += __shfl_xor(vn, 2);  vn  += __shfl_xor(vn, 4);
    if (g == 0) {
      float den = fmaxf(sqrtf(wn) * sqrtf(vn), EPSF);
      float rs = num / den;
      red[t] = (t < len) ? __expf(G2 * rs) : 0.f;
    }
  }
  __syncthreads();

  if (tid == 0) {
    float ssum = 0.f;
#pragma unroll
    for (int t = 0; t < Tn; ++t) ssum += red[t];
    sims[i * Bn + b] = logf(ssum);
  }
}

// ---------------------------------------------------------------------------
// Loss kernel (fallback path only): masked double log-softmax over sims.
// ---------------------------------------------------------------------------
__global__ __launch_bounds__(64) void k_loss(const float* __restrict__ sims,
                                             const int* __restrict__ labels,
                                             const int* __restrict__ class_ids,
                                             float* __restrict__ out) {
  const int r = threadIdx.x;
  const int cr = class_ids[r];
  const int lab = labels[r];

  float m0 = NEGF;
  for (int c = 0; c < Bn; ++c) {
    float v = sims[c * Bn + r] * G3;
    if (class_ids[c] == cr && c != r) v = NEGF;
    m0 = fmaxf(m0, v);
  }
  float se0 = 0.f, tgt0 = 0.f;
  for (int c = 0; c < Bn; ++c) {
    float v = sims[c * Bn + r] * G3;
    if (class_ids[c] == cr && c != r) v = NEGF;
    se0 += __expf(v - m0);
    if (c == lab) tgt0 = v;
  }
  float val0 = tgt0 - (m0 + logf(se0));

  float m1 = NEGF;
  for (int c = 0; c < Bn; ++c) {
    float v = sims[r * Bn + c] * G3;
    if (class_ids[c] == cr && c != r) v = NEGF;
    m1 = fmaxf(m1, v);
  }
  float se1 = 0.f, tgt1 = 0.f;
  for (int c = 0; c < Bn; ++c) {
    float v = sims[r * Bn + c] * G3;
    if (class_ids[c] == cr && c != r) v = NEGF;
    se1 += __expf(v - m1);
    if (c == lab) tgt1 = v;
  }
  float val1 = tgt1 - (m1 + logf(se1));

  for (int off = 1; off < 64; off <<= 1) {
    val0 += __shfl_xor(val0, off);
    val1 += __shfl_xor(val1, off);
  }
  if (r == 0) {
    out[0] = -val0 / (float)Bn;
    out[1] = -val1 / (float)Bn;
  }
}

// ---------------------------------------------------------------------------
extern "C" void kernel_launch(void* const* d_in, const int* in_sizes, int n_in,
                              void* d_out, int out_size, void* d_ws, size_t ws_size,
                              hipStream_t stream) {
  const float* img      = (const float*)d_in[0];  // (B,D,R,R)
  const float* words    = (const float*)d_in[1];  // (B,D,T)
  const int*   labels   = (const int*)d_in[2];
  const int*   cap_lens = (const int*)d_in[3];
  const int*   class_ids= (const int*)d_in[4];
  float* out = (float*)d_out;                     // [loss0, loss1, att_maps...]

  float* sims = (float*)d_ws;
  size_t off = (size_t)Bn * Bn * sizeof(float);         // 16 KB
  const size_t AhB = (size_t)Bn * MT_A * KK_A * 512 * 2;  // 9.96 MB each
  const size_t ChB = (size_t)Bn * DT_B * KK_B * 512 * 2;  // 10.49 MB each
  const size_t WhB = (size_t)Bn * KK_A * 2 * 512 * 2;     // 1.05 MB each
  short* Ahf = (short*)((char*)d_ws + off); off += AhB;
  short* Alf = (short*)((char*)d_ws + off); off += AhB;
  short* Chf = (short*)((char*)d_ws + off); off += ChB;
  short* Clf = (short*)((char*)d_ws + off); off += ChB;
  short* Whf = (short*)((char*)d_ws + off); off += WhB;
  short* Wlf = (short*)((char*)d_ws + off); off += WhB;   // ~43.0 MB
  unsigned* cnt = (unsigned*)((char*)d_ws + off); off += 256;

  if (ws_size >= off) {
    // MFMA path: fused prep (ctx + W + counter reset), fused main+loss.
    kprep_ctx<<<Bn * 8 + 8, 256, 0, stream>>>(img, words, Ahf, Alf, Chf, Clf,
                                              Whf, Wlf, cnt);
    k_main8<<<Bn * Bn, 512, 0, stream>>>(Ahf, Alf, Chf, Clf, Whf, Wlf,
                                         words, cap_lens, labels, class_ids,
                                         cnt, sims, out, out + 2);
  } else {
    // VALU fallback (round-4 path)
    const size_t simsB = (size_t)Bn * Bn * sizeof(float);
    const size_t ctxTB = (size_t)Bn * Sn * Dn * sizeof(float);
    float* ctxT = (float*)((char*)d_ws + simsB);
    const bool useT = ws_size >= simsB + ctxTB;
    const float* g2 = img;
    int tstr = Sn, sstr = 1;
    if (useT) {
      dim3 tb(32, 8);
      dim3 tg((Sn + 31) / 32, Dn / 32, Bn);
      k_transpose<<<tg, tb, 0, stream>>>(img, ctxT);
      g2 = ctxT; tstr = 1; sstr = Dn;
    }
    k_main_valu<<<Bn * Bn, NT, 0, stream>>>(img, words, g2, tstr, sstr,
                                            cap_lens, sims, out + 2);
    k_loss<<<1, 64, 0, stream>>>(sims, labels, class_ids, out);
  }
}

// Round 11
// 289.508 us; speedup vs baseline: 1.3911x; 1.3911x over previous
//
#include <hip/hip_runtime.h>
#include <math.h>

// Problem constants (match reference)
namespace {
constexpr int Bn = 64;    // batch
constexpr int Dn = 256;   // feature dim
constexpr int Tn = 24;    // words
constexpr int Rn = 17;
constexpr int Sn = Rn * Rn;  // 289 spatial
constexpr float G1 = 4.0f, G2 = 5.0f, G3 = 10.0f;
constexpr float EPSF = 1e-8f;
constexpr float NEGF = -1e30f;
// MFMA-path geometry
constexpr int MT_A = 19;   // GEMM-A m-tiles (304 rows of s)
constexpr int KK_A = 8;    // GEMM-A k-steps (256 = 8*32 over d)
constexpr int DT_B = 16;   // GEMM-B m-tiles (256 rows of d)
constexpr int KK_B = 10;   // GEMM-B k-steps (320 = 10*32 over s)
constexpr int ESTR = 344;  // EH/EL row stride (shorts): 688 B rows
constexpr int PSTR = 305;  // P row stride (floats) inside union
constexpr int TSTR = 293;  // prep LDS tile stride (floats)
// VALU-fallback constants (round-4 kernel, known-correct)
constexpr int WSTR = 24;
constexpr int ASTR = 24;
constexpr int NT = 320;
}

typedef __attribute__((ext_vector_type(8))) short bf16x8;  // 8 bf16 (4 VGPRs)
typedef __attribute__((ext_vector_type(4))) float f32x4;   // 4 fp32 acc

#define MFMA_BF16 __builtin_amdgcn_mfma_f32_16x16x32_bf16

// RNE float -> bf16 bits (bit-twiddle; no NaN inputs here)
__device__ __forceinline__ short f2bf(float x) {
  unsigned u = __float_as_uint(x);
  return (short)((u + 0x7FFFu + ((u >> 16) & 1u)) >> 16);
}
__device__ __forceinline__ float bf2f(short h) {
  return __uint_as_float(((unsigned)(unsigned short)h) << 16);
}

// ---------------------------------------------------------------------------
// Fused prep: blocks [0, Bn*8) handle ctx (A-frags + C-frags via LDS tile);
// blocks [Bn*8, Bn*8+8) handle W-frags.
// ---------------------------------------------------------------------------
__global__ __launch_bounds__(256) void kprep_ctx(const float* __restrict__ ctx,
                                                 const float* __restrict__ words,
                                                 short* __restrict__ Ahf,
                                                 short* __restrict__ Alf,
                                                 short* __restrict__ Chf,
                                                 short* __restrict__ Clf,
                                                 short* __restrict__ Whf,
                                                 short* __restrict__ Wlf) {
  __shared__ float tile[32][TSTR];  // 37.5 KB
  const int tid = threadIdx.x;

  if (blockIdx.x >= Bn * 8) {
    // ---- W-frags: [i][kk][n][lane][8]; lane holds W[n*16+l15][kk*32+lg*8+e]
    const int wb = blockIdx.x - Bn * 8;  // 0..7
    const int total = Bn * KK_A * 2 * 64;
    for (int gid = wb * 256 + tid; gid < total; gid += 8 * 256) {
      const int lane = gid & 63;
      int f = gid >> 6;
      const int n = f & 1; f >>= 1;
      const int kk = f & 7;
      const int i = f >> 3;
      const int t = n * 16 + (lane & 15);
      const int d0 = kk * 32 + (lane >> 4) * 8;
      bf16x8 hi, lo;
#pragma unroll
      for (int e = 0; e < 8; ++e) {
        float v = (t < Tn) ? words[((size_t)i * Dn + d0 + e) * Tn + t] : 0.f;
        short h = f2bf(v);
        hi[e] = h;
        lo[e] = f2bf(v - bf2f(h));
      }
      *(bf16x8*)&Whf[(size_t)gid * 8] = hi;
      *(bf16x8*)&Wlf[(size_t)gid * 8] = lo;
    }
    return;
  }

  const int b = blockIdx.x >> 3;
  const int d0b = blockIdx.x & 7;   // d-block index (= GEMM-A k-step kkA)
  const int d0 = d0b * 32;
  const int tx = tid & 31, ty = tid >> 5;

  // ---- stage: 32 lanes read 32 consecutive floats per row (coalesced)
  for (int r = ty; r < 32; r += 8) {
    const float* src = ctx + ((size_t)b * Dn + d0 + r) * Sn;
    for (int s = tx; s < Sn; s += 32) tile[r][s] = src[s];
  }
  __syncthreads();

  // ---- emit A-frags: 19 mt x 64 lanes; value e: tile[lg*8+e][mt*16+l15]
  for (int slot = tid; slot < MT_A * 64; slot += 256) {
    const int mt = slot >> 6;
    const int lane = slot & 63;
    const int s = mt * 16 + (lane & 15);
    const int dl = (lane >> 4) * 8;
    bf16x8 hi, lo;
#pragma unroll
    for (int e = 0; e < 8; ++e) {
      float v = (s < Sn) ? tile[dl + e][s] : 0.f;
      short h = f2bf(v);
      hi[e] = h;
      lo[e] = f2bf(v - bf2f(h));
    }
    const size_t gid = ((size_t)(b * MT_A + mt) * KK_A + d0b) * 64 + lane;
    *(bf16x8*)&Ahf[gid * 8] = hi;
    *(bf16x8*)&Alf[gid * 8] = lo;
  }

  // ---- emit C-frags: 2 dt x 10 kk x 64 lanes; value e: tile[dtl*16+l15][s0+e]
  for (int slot = tid; slot < 2 * KK_B * 64; slot += 256) {
    const int lane = slot & 63;
    const int f = slot >> 6;
    const int kk = f % KK_B;
    const int dtl = f / KK_B;
    const int dloc = dtl * 16 + (lane & 15);
    const int s0 = kk * 32 + (lane >> 4) * 8;
    bf16x8 hi, lo;
#pragma unroll
    for (int e = 0; e < 8; ++e) {
      const int s = s0 + e;
      float v = (s < Sn) ? tile[dloc][s] : 0.f;
      short h = f2bf(v);
      hi[e] = h;
      lo[e] = f2bf(v - bf2f(h));
    }
    const size_t gid = ((size_t)(b * DT_B + (d0b * 2 + dtl)) * KK_B + kk) * 64 + lane;
    *(bf16x8*)&Chf[gid * 8] = hi;
    *(bf16x8*)&Clf[gid * 8] = lo;
  }
}

// ---------------------------------------------------------------------------
// Main MFMA kernel: one 512-thread block (8 waves) per (i,b) pair.
// Round-10: body is the round-8 known-good version (unroll 2, no fence, no
// fused loss). ONE change: XCD-aware block swizzle so all blocks resident on
// one XCD share a b-group (A/C-frags L2-resident).
//   chunk = bid>>3; i = chunk&63; b = (bid&7)*8 + (chunk>>6)   (bijective)
// Fragment layout (guide §3, m89-verified C/D):
//   A: row m = lane&15, k = (lane>>4)*8+e ; B: col n = lane&15, same k
//   C/D: col n = lane&15, row m = (lane>>4)*4 + reg
// ---------------------------------------------------------------------------
__global__ __launch_bounds__(512, 6) void k_main8(
    const short* __restrict__ Ahf, const short* __restrict__ Alf,
    const short* __restrict__ Chf, const short* __restrict__ Clf,
    const short* __restrict__ Whf, const short* __restrict__ Wlf,
    const float* __restrict__ words, const int* __restrict__ cap_lens,
    float* __restrict__ sims, float* __restrict__ att_out)
{
  __shared__ __align__(16) short U[2][32][ESTR];  // 44,032 B: EH=U[0], EL=U[1]
  __shared__ float inv2s[32];
  __shared__ float redN[Tn], redV[Tn], redW[Tn], redE[Tn];
  float (*P)[PSTR] = (float (*)[PSTR]) & U[0][0][0];  // aliases U; dead before EH/EL live

  const int bid = blockIdx.x;
  const int chunk = bid >> 3;
  const int i = chunk & 63;                      // word batch index
  const int b = (bid & 7) * 8 + (chunk >> 6);    // image batch: b-group per XCD
  const int tid = threadIdx.x;
  const int lane = tid & 63;
  const int wv = tid >> 6;              // wave 0..7
  const int l15 = lane & 15, lg = lane >> 4;
  const int len = cap_lens[i];

  if (tid < Tn) { redN[tid] = 0.f; redV[tid] = 0.f; redW[tid] = 0.f; }

  // ============ GEMM-A: logits[s][t] = sum_d ctxT[s][d] * W^T[t][d]
  f32x4 acc[3][2];
#pragma unroll
  for (int j = 0; j < 3; ++j) {
    acc[j][0] = f32x4{0.f, 0.f, 0.f, 0.f};
    acc[j][1] = f32x4{0.f, 0.f, 0.f, 0.f};
  }
#pragma unroll 2
  for (int kk = 0; kk < KK_A; ++kk) {
    const size_t Wb = ((size_t)(i * KK_A + kk) * 2) * 512 + (size_t)lane * 8;
    bf16x8 bh0 = *(const bf16x8*)&Whf[Wb];
    bf16x8 bl0 = *(const bf16x8*)&Wlf[Wb];
    bf16x8 bh1 = *(const bf16x8*)&Whf[Wb + 512];
    bf16x8 bl1 = *(const bf16x8*)&Wlf[Wb + 512];
#pragma unroll
    for (int j = 0; j < 3; ++j) {
      const int mt = wv + j * 8;            // wave's m-tiles: w, w+8, w+16
      if (mt < MT_A) {
        const size_t Ab = ((size_t)(b * MT_A + mt) * KK_A + kk) * 512 + (size_t)lane * 8;
        bf16x8 ah = *(const bf16x8*)&Ahf[Ab];
        bf16x8 al = *(const bf16x8*)&Alf[Ab];
        __builtin_amdgcn_s_setprio(1);
        acc[j][0] = MFMA_BF16(ah, bh0, acc[j][0], 0, 0, 0);
        acc[j][0] = MFMA_BF16(ah, bl0, acc[j][0], 0, 0, 0);
        acc[j][0] = MFMA_BF16(al, bh0, acc[j][0], 0, 0, 0);
        acc[j][1] = MFMA_BF16(ah, bh1, acc[j][1], 0, 0, 0);
        acc[j][1] = MFMA_BF16(ah, bl1, acc[j][1], 0, 0, 0);
        acc[j][1] = MFMA_BF16(al, bh1, acc[j][1], 0, 0, 0);
        __builtin_amdgcn_s_setprio(0);
      }
    }
  }

  // ---- softmax-1 over t (masked t<len), fully in registers; write p1 to P.
  //      Row s = mt*16 + lg*4 + q lives in the 16 lanes of group lg, reg q.
  const int t0 = l15, t1 = 16 + l15;
#pragma unroll
  for (int j = 0; j < 3; ++j) {
    const int mt = wv + j * 8;
    if (mt >= MT_A) continue;
    float mx[4], e0[4], e1[4], sum[4];
#pragma unroll
    for (int q = 0; q < 4; ++q) {
      float a = (t0 < len) ? acc[j][0][q] : NEGF;
      float c = (t1 < len) ? acc[j][1][q] : NEGF;
      mx[q] = fmaxf(a, c);
    }
#pragma unroll
    for (int q = 0; q < 4; ++q) {
      mx[q] = fmaxf(mx[q], __shfl_xor(mx[q], 1));
      mx[q] = fmaxf(mx[q], __shfl_xor(mx[q], 2));
      mx[q] = fmaxf(mx[q], __shfl_xor(mx[q], 4));
      mx[q] = fmaxf(mx[q], __shfl_xor(mx[q], 8));
    }
#pragma unroll
    for (int q = 0; q < 4; ++q) {
      e0[q] = (t0 < len) ? __expf(acc[j][0][q] - mx[q]) : 0.f;
      e1[q] = (t1 < len) ? __expf(acc[j][1][q] - mx[q]) : 0.f;
      sum[q] = e0[q] + e1[q];
    }
#pragma unroll
    for (int q = 0; q < 4; ++q) {
      sum[q] += __shfl_xor(sum[q], 1);
      sum[q] += __shfl_xor(sum[q], 2);
      sum[q] += __shfl_xor(sum[q], 4);
      sum[q] += __shfl_xor(sum[q], 8);
    }
#pragma unroll
    for (int q = 0; q < 4; ++q) {
      const int s = mt * 16 + lg * 4 + q;
      const float inv = 1.f / sum[q];
      if (s < Sn) {
        P[t0][s] = e0[q] * inv;
        if (l15 < 8) P[t1][s] = e1[q] * inv;  // t 16..23
      }
    }
  }
  __syncthreads();  // P complete

  // ---- softmax-2 over s (per t), register-buffered so EH/EL can reuse P's LDS.
  const int t2 = tid >> 4;      // 16 lanes per t
  const int g2i = tid & 15;
  float ev[19];
  float sinv = 0.f;
  if (t2 < Tn) {
    float mx = NEGF;
#pragma unroll
    for (int k = 0; k < 19; ++k) {
      const int s = g2i + 16 * k;
      ev[k] = (s < Sn) ? P[t2][s] : NEGF;
      mx = fmaxf(mx, ev[k]);
    }
    mx = fmaxf(mx, __shfl_xor(mx, 1));
    mx = fmaxf(mx, __shfl_xor(mx, 2));
    mx = fmaxf(mx, __shfl_xor(mx, 4));
    mx = fmaxf(mx, __shfl_xor(mx, 8));
    mx *= G1;  // exact: G1 = 4.0 is a power of two
    float sum = 0.f;
#pragma unroll
    for (int k = 0; k < 19; ++k) {
      const int s = g2i + 16 * k;
      float e = (s < Sn) ? __expf(G1 * ev[k] - mx) : 0.f;
      ev[k] = e;  // overwrite with unnormalized e2
      sum += e;
    }
    sum += __shfl_xor(sum, 1);
    sum += __shfl_xor(sum, 2);
    sum += __shfl_xor(sum, 4);
    sum += __shfl_xor(sum, 8);
    sinv = 1.f / sum;
    if (g2i == 0) inv2s[t2] = sinv;
  }
  __syncthreads();  // all P reads done; U now owned by EH/EL

  // ---- Phase 2: write e2 split-bf16 into EH/EL; zero pad; att_maps on diag.
  if (t2 < Tn) {
#pragma unroll
    for (int k = 0; k < 19; ++k) {
      const int s = g2i + 16 * k;
      if (s < Sn) {
        float e = ev[k];
        short h = f2bf(e);
        U[0][t2][s] = h;
        U[1][t2][s] = f2bf(e - bf2f(h));
      }
    }
    if (i == b) {
      float* ao = att_out + ((size_t)i * Tn + t2) * Sn;
#pragma unroll
      for (int k = 0; k < 19; ++k) {
        const int s = g2i + 16 * k;
        if (s < Sn) ao[s] = ev[k] * sinv;
      }
    }
  }
  // zero k-pad cols [289,320) rows 0..23, and full rows 24..31 (both buffers)
  for (int idx = tid; idx < 24 * 31; idx += 512) {
    const int r = idx / 31, c = 289 + idx % 31;
    U[0][r][c] = 0; U[1][r][c] = 0;
  }
  for (int idx = tid; idx < 8 * ESTR; idx += 512) {
    const int r = 24 + idx / ESTR, c = idx % ESTR;
    U[0][r][c] = 0; U[1][r][c] = 0;
  }
  __syncthreads();

  // ============ GEMM-B: wei[d][t] = sum_s ctx[b][d][s] * e2[t][s]
  f32x4 acc2[2][2];
#pragma unroll
  for (int j = 0; j < 2; ++j) {
    acc2[j][0] = f32x4{0.f, 0.f, 0.f, 0.f};
    acc2[j][1] = f32x4{0.f, 0.f, 0.f, 0.f};
  }
#pragma unroll 2
  for (int kk = 0; kk < KK_B; ++kk) {
    const int k0 = kk * 32 + lg * 8;
    bf16x8 bh0 = *(const bf16x8*)&U[0][l15][k0];
    bf16x8 bl0 = *(const bf16x8*)&U[1][l15][k0];
    bf16x8 bh1 = *(const bf16x8*)&U[0][16 + l15][k0];
    bf16x8 bl1 = *(const bf16x8*)&U[1][16 + l15][k0];
#pragma unroll
    for (int j = 0; j < 2; ++j) {
      const int dt = wv + j * 8;            // d-tiles: w, w+8
      const size_t Cb = ((size_t)(b * DT_B + dt) * KK_B + kk) * 512 + (size_t)lane * 8;
      bf16x8 ah = *(const bf16x8*)&Chf[Cb];
      bf16x8 al = *(const bf16x8*)&Clf[Cb];
      __builtin_amdgcn_s_setprio(1);
      acc2[j][0] = MFMA_BF16(ah, bh0, acc2[j][0], 0, 0, 0);
      acc2[j][0] = MFMA_BF16(ah, bl0, acc2[j][0], 0, 0, 0);
      acc2[j][0] = MFMA_BF16(al, bh0, acc2[j][0], 0, 0, 0);
      acc2[j][1] = MFMA_BF16(ah, bh1, acc2[j][1], 0, 0, 0);
      acc2[j][1] = MFMA_BF16(ah, bl1, acc2[j][1], 0, 0, 0);
      acc2[j][1] = MFMA_BF16(al, bh1, acc2[j][1], 0, 0, 0);
      __builtin_amdgcn_s_setprio(0);
    }
  }

  // ---- cosine similarity: per t reduce num/|wei|^2/|w|^2 over d
  float pn[2] = {0.f, 0.f}, pv[2] = {0.f, 0.f}, pw[2] = {0.f, 0.f};
#pragma unroll
  for (int nt = 0; nt < 2; ++nt) {
    const int t = nt * 16 + l15;
    const bool tv = (t < Tn);
    const float iv = tv ? inv2s[t] : 0.f;
#pragma unroll
    for (int j = 0; j < 2; ++j) {
#pragma unroll
      for (int q = 0; q < 4; ++q) {
        const int d = (wv + j * 8) * 16 + lg * 4 + q;
        const float wei = acc2[j][nt][q] * iv;
        const float wvv = tv ? words[((size_t)i * Dn + d) * Tn + t] : 0.f;
        pn[nt] = fmaf(wvv, wei, pn[nt]);
        pv[nt] = fmaf(wei, wei, pv[nt]);
        pw[nt] = fmaf(wvv, wvv, pw[nt]);
      }
    }
  }
#pragma unroll
  for (int nt = 0; nt < 2; ++nt) {
    pn[nt] += __shfl_xor(pn[nt], 16); pn[nt] += __shfl_xor(pn[nt], 32);
    pv[nt] += __shfl_xor(pv[nt], 16); pv[nt] += __shfl_xor(pv[nt], 32);
    pw[nt] += __shfl_xor(pw[nt], 16); pw[nt] += __shfl_xor(pw[nt], 32);
  }
  if (lg == 0) {
#pragma unroll
    for (int nt = 0; nt < 2; ++nt) {
      const int t = nt * 16 + l15;
      if (t < Tn) {
        atomicAdd(&redN[t], pn[nt]);
        atomicAdd(&redV[t], pv[nt]);
        atomicAdd(&redW[t], pw[nt]);
      }
    }
  }
  __syncthreads();
  if (tid < Tn) {
    const float den = fmaxf(sqrtf(redW[tid]) * sqrtf(redV[tid]), EPSF);
    const float rs = redN[tid] / den;
    redE[tid] = (tid < len) ? __expf(G2 * rs) : 0.f;
  }
  __syncthreads();
  if (tid == 0) {
    float ssum = 0.f;
#pragma unroll
    for (int t = 0; t < Tn; ++t) ssum += redE[t];
    sims[i * Bn + b] = logf(ssum);
  }
}

// ---------------------------------------------------------------------------
// VALU fallback path (round-4 kernels, known-correct) — used if ws too small.
// ---------------------------------------------------------------------------
__device__ __forceinline__ void fma24(float v, const float* __restrict__ row,
                                      float* __restrict__ acc) {
#pragma unroll
  for (int t = 0; t < Tn; ++t) acc[t] = fmaf(v, row[t], acc[t]);
}

__global__ __launch_bounds__(256) void k_transpose(const float* __restrict__ ctx,
                                                   float* __restrict__ ctxT) {
  __shared__ float tile[32][33];
  const int b = blockIdx.z;
  const int x0 = blockIdx.x * 32;
  const int y0 = blockIdx.y * 32;
  const int tx = threadIdx.x, ty = threadIdx.y;
  const float* src = ctx + (size_t)b * Dn * Sn;
  float* dst = ctxT + (size_t)b * Sn * Dn;
#pragma unroll
  for (int k = 0; k < 4; ++k) {
    int y = y0 + ty + k * 8, x = x0 + tx;
    if (x < Sn) tile[ty + k * 8][tx] = src[(size_t)y * Sn + x];
  }
  __syncthreads();
#pragma unroll
  for (int k = 0; k < 4; ++k) {
    int x = x0 + ty + k * 8, y = y0 + tx;
    if (x < Sn) dst[(size_t)x * Dn + y] = tile[tx][ty + k * 8];
  }
}

__global__ __launch_bounds__(NT) void k_main_valu(
    const float* __restrict__ ctx, const float* __restrict__ words,
    const float* __restrict__ g2, int tstr, int sstr,
    const int* __restrict__ cap_lens,
    float* __restrict__ sims, float* __restrict__ att_out)
{
  __shared__ __align__(16) float Wl[Dn * WSTR];
  __shared__ __align__(16) float AT[Sn * ASTR];
  __shared__ float inv2[Tn];
  __shared__ float red[Tn];

  const int bid = blockIdx.x;
  const int i = bid & 63, b = bid >> 6;
  const int tid = threadIdx.x;
  const int len = cap_lens[i];

  {
    const float4* wsrc = (const float4*)(words + (size_t)i * Dn * Tn);
    float4* wdst = (float4*)Wl;
    for (int k = tid; k < Dn * Tn / 4; k += NT) wdst[k] = wsrc[k];
  }
  __syncthreads();

  if (tid < Sn) {
    float acc[Tn];
#pragma unroll
    for (int t = 0; t < Tn; ++t) acc[t] = 0.f;
    const float* cb = ctx + (size_t)b * Dn * Sn + tid;
    float v0 = cb[0], v1 = cb[Sn];
    int d = 0;
    for (; d < Dn - 2; d += 2) {
      float n0 = cb[(size_t)(d + 2) * Sn];
      float n1 = cb[(size_t)(d + 3) * Sn];
      fma24(v0, &Wl[d * WSTR], acc);
      fma24(v1, &Wl[(d + 1) * WSTR], acc);
      v0 = n0; v1 = n1;
    }
    fma24(v0, &Wl[d * WSTR], acc);
    fma24(v1, &Wl[(d + 1) * WSTR], acc);
    float m = NEGF;
#pragma unroll
    for (int t = 0; t < Tn; ++t)
      if (t < len) m = fmaxf(m, acc[t]);
    float sum = 0.f;
#pragma unroll
    for (int t = 0; t < Tn; ++t) {
      float e = (t < len) ? __expf(acc[t] - m) : 0.f;
      acc[t] = e; sum += e;
    }
    const float inv = 1.f / sum;
#pragma unroll
    for (int t = 0; t < Tn; ++t) AT[tid * ASTR + t] = acc[t] * inv;
  }
  __syncthreads();

  if (tid < Tn * 8) {
    const int t = tid >> 3, g = tid & 7;
    float m = NEGF;
    for (int ss = g; ss < Sn; ss += 8) m = fmaxf(m, AT[ss * ASTR + t]);
    m = fmaxf(m, __shfl_xor(m, 1));
    m = fmaxf(m, __shfl_xor(m, 2));
    m = fmaxf(m, __shfl_xor(m, 4));
    m *= G1;
    float sum = 0.f;
    for (int ss = g; ss < Sn; ss += 8) {
      float e = __expf(G1 * AT[ss * ASTR + t] - m);
      AT[ss * ASTR + t] = e;
      sum += e;
    }
    sum += __shfl_xor(sum, 1);
    sum += __shfl_xor(sum, 2);
    sum += __shfl_xor(sum, 4);
    if (g == 0) inv2[t] = 1.f / sum;
  }
  __syncthreads();

  float acc2[Tn];
  if (tid < Dn) {
#pragma unroll
    for (int t = 0; t < Tn; ++t) acc2[t] = 0.f;
    const float* src = g2 + (size_t)b * Dn * Sn + (size_t)tid * tstr;
    const size_t s1 = sstr, s2 = 2 * (size_t)sstr, s3 = 3 * (size_t)sstr,
                 s4 = 4 * (size_t)sstr;
    float p0 = src[0], p1 = src[s1], p2 = src[s2], p3 = src[s3];
    const float* nsrc = src + s4;
    int ss = 0;
    for (; ss < 284; ss += 4) {
      float n0 = nsrc[0], n1 = nsrc[s1], n2 = nsrc[s2], n3 = nsrc[s3];
      fma24(p0, &AT[ss * ASTR], acc2);
      fma24(p1, &AT[(ss + 1) * ASTR], acc2);
      fma24(p2, &AT[(ss + 2) * ASTR], acc2);
      fma24(p3, &AT[(ss + 3) * ASTR], acc2);
      p0 = n0; p1 = n1; p2 = n2; p3 = n3;
      nsrc += s4;
    }
    fma24(p0, &AT[284 * ASTR], acc2);
    fma24(p1, &AT[285 * ASTR], acc2);
    fma24(p2, &AT[286 * ASTR], acc2);
    fma24(p3, &AT[287 * ASTR], acc2);
    {
      float v = src[(size_t)288 * sstr];
      fma24(v, &AT[288 * ASTR], acc2);
    }
#pragma unroll
    for (int t = 0; t < Tn; ++t) acc2[t] *= inv2[t];
  }

  if (i == b) {
#pragma unroll 1
    for (int t = 0; t < Tn; ++t) {
      const float iv = inv2[t];
      for (int ss = tid; ss < Sn; ss += NT)
        att_out[(size_t)i * Tn * Sn + (size_t)t * Sn + ss] = AT[ss * ASTR + t] * iv;
    }
  }
  __syncthreads();

  if (tid < Dn) {
#pragma unroll
    for (int t = 0; t < Tn; ++t) AT[tid * ASTR + t] = acc2[t];
  }
  __syncthreads();

  if (tid < Tn * 8) {
    const int t = tid >> 3, g = tid & 7;
    float num = 0.f, wn = 0.f, vn = 0.f;
    for (int dd = g; dd < Dn; dd += 8) {
      float wvv = Wl[dd * WSTR + t];
      float uv = AT[dd * ASTR + t];
      num = fmaf(wvv, uv, num);
      wn = fmaf(wvv, wvv, wn);
      vn = fmaf(uv, uv, vn);
    }
    num += __shfl_xor(num, 1); num += __shfl_xor(num, 2); num += __shfl_xor(num, 4);
    wn  += __shfl_xor(wn, 1);  wn  += __shfl_xor(wn, 2);  wn  += __shfl_xor(wn, 4);
    vn  += __shfl_xor(vn, 1);  vn  += __shfl_xor(vn, 2);  vn  += __shfl_xor(vn, 4);
    if (g == 0) {
      float den = fmaxf(sqrtf(wn) * sqrtf(vn), EPSF);
      float rs = num / den;
      red[t] = (t < len) ? __expf(G2 * rs) : 0.f;
    }
  }
  __syncthreads();

  if (tid == 0) {
    float ssum = 0.f;
#pragma unroll
    for (int t = 0; t < Tn; ++t) ssum += red[t];
    sims[i * Bn + b] = logf(ssum);
  }
}

// ---------------------------------------------------------------------------
// Loss kernel: masked double log-softmax over 64x64 sims. 1 wave.
// ---------------------------------------------------------------------------
__global__ __launch_bounds__(64) void k_loss(const float* __restrict__ sims,
                                             const int* __restrict__ labels,
                                             const int* __restrict__ class_ids,
                                             float* __restrict__ out) {
  const int r = threadIdx.x;
  const int cr = class_ids[r];
  const int lab = labels[r];

  float m0 = NEGF;
  for (int c = 0; c < Bn; ++c) {
    float v = sims[c * Bn + r] * G3;
    if (class_ids[c] == cr && c != r) v = NEGF;
    m0 = fmaxf(m0, v);
  }
  float se0 = 0.f, tgt0 = 0.f;
  for (int c = 0; c < Bn; ++c) {
    float v = sims[c * Bn + r] * G3;
    if (class_ids[c] == cr && c != r) v = NEGF;
    se0 += __expf(v - m0);
    if (c == lab) tgt0 = v;
  }
  float val0 = tgt0 - (m0 + logf(se0));

  float m1 = NEGF;
  for (int c = 0; c < Bn; ++c) {
    float v = sims[r * Bn + c] * G3;
    if (class_ids[c] == cr && c != r) v = NEGF;
    m1 = fmaxf(m1, v);
  }
  float se1 = 0.f, tgt1 = 0.f;
  for (int c = 0; c < Bn; ++c) {
    float v = sims[r * Bn + c] * G3;
    if (class_ids[c] == cr && c != r) v = NEGF;
    se1 += __expf(v - m1);
    if (c == lab) tgt1 = v;
  }
  float val1 = tgt1 - (m1 + logf(se1));

  for (int off = 1; off < 64; off <<= 1) {
    val0 += __shfl_xor(val0, off);
    val1 += __shfl_xor(val1, off);
  }
  if (r == 0) {
    out[0] = -val0 / (float)Bn;
    out[1] = -val1 / (float)Bn;
  }
}

// ---------------------------------------------------------------------------
extern "C" void kernel_launch(void* const* d_in, const int* in_sizes, int n_in,
                              void* d_out, int out_size, void* d_ws, size_t ws_size,
                              hipStream_t stream) {
  const float* img      = (const float*)d_in[0];  // (B,D,R,R)
  const float* words    = (const float*)d_in[1];  // (B,D,T)
  const int*   labels   = (const int*)d_in[2];
  const int*   cap_lens = (const int*)d_in[3];
  const int*   class_ids= (const int*)d_in[4];
  float* out = (float*)d_out;                     // [loss0, loss1, att_maps...]

  float* sims = (float*)d_ws;
  size_t off = (size_t)Bn * Bn * sizeof(float);         // 16 KB
  const size_t AhB = (size_t)Bn * MT_A * KK_A * 512 * 2;  // 9.96 MB each
  const size_t ChB = (size_t)Bn * DT_B * KK_B * 512 * 2;  // 10.49 MB each
  const size_t WhB = (size_t)Bn * KK_A * 2 * 512 * 2;     // 1.05 MB each
  short* Ahf = (short*)((char*)d_ws + off); off += AhB;
  short* Alf = (short*)((char*)d_ws + off); off += AhB;
  short* Chf = (short*)((char*)d_ws + off); off += ChB;
  short* Clf = (short*)((char*)d_ws + off); off += ChB;
  short* Whf = (short*)((char*)d_ws + off); off += WhB;
  short* Wlf = (short*)((char*)d_ws + off); off += WhB;   // ~43.0 MB

  if (ws_size >= off) {
    // MFMA path: fused prep (ctx + W), round-8 main + XCD swizzle, separate loss.
    kprep_ctx<<<Bn * 8 + 8, 256, 0, stream>>>(img, words, Ahf, Alf, Chf, Clf,
                                              Whf, Wlf);
    k_main8<<<Bn * Bn, 512, 0, stream>>>(Ahf, Alf, Chf, Clf, Whf, Wlf,
                                         words, cap_lens, sims, out + 2);
    k_loss<<<1, 64, 0, stream>>>(sims, labels, class_ids, out);
  } else {
    // VALU fallback (round-4 path)
    const size_t simsB = (size_t)Bn * Bn * sizeof(float);
    const size_t ctxTB = (size_t)Bn * Sn * Dn * sizeof(float);
    float* ctxT = (float*)((char*)d_ws + simsB);
    const bool useT = ws_size >= simsB + ctxTB;
    const float* g2 = img;
    int tstr = Sn, sstr = 1;
    if (useT) {
      dim3 tb(32, 8);
      dim3 tg((Sn + 31) / 32, Dn / 32, Bn);
      k_transpose<<<tg, tb, 0, stream>>>(img, ctxT);
      g2 = ctxT; tstr = 1; sstr = Dn;
    }
    k_main_valu<<<Bn * Bn, NT, 0, stream>>>(img, words, g2, tstr, sstr,
                                            cap_lens, sims, out + 2);
    k_loss<<<1, 64, 0, stream>>>(sims, labels, class_ids, out);
  }
}